// Round 1
// baseline (1876.658 us; speedup 1.0000x reference)
//
#include <hip/hip_runtime.h>
#include <math.h>

#define NI 128
#define NC 256
#define NR 36
#define NW 48
#define ND 256
#define G  2          // captions per block
#define NWG (G*NW)    // 96

// LDS pitches (floats)
#define PI 260        // sI pitch: %4==0 for float4, (260%32)=4 breaks pow2 strides
#define PC 257        // sC pitch: odd -> conflict-free row-wise scalar access
#define PA 50         // attn buffer a[cg][r][w] pitch
#define PP 37         // pT[cg][w][r] pitch (overlaid on attn buffer)

__global__ __launch_bounds__(256, 1)
void scan_kernel(const float* __restrict__ images,
                 const float* __restrict__ captions,
                 float* __restrict__ out)
{
    __shared__ float sI[NR * PI];      // 9360 f  = 37.4 KB
    __shared__ float sC[NWG * PC];     // 24672 f = 98.7 KB
    __shared__ float sA[2 * 1800];     // 3600 f: a[cg][r][w] then overlaid pT[cg][w][r]
    __shared__ float invn[G * NR];     // 72
    __shared__ float w12s[NWG];
    __shared__ float w2s[NWG];
    __shared__ float rs[NWG];

    const int tid = threadIdx.x;
    const int i   = blockIdx.y;
    const int c0  = blockIdx.x * G;

    // ---- stage images[i] -> sI (coalesced float4) ----
    const float* gI = images + (size_t)i * NR * ND;
    #pragma unroll
    for (int q = 0; q < 9; ++q) {
        int e = (q * 256 + tid) * 4;           // 0..9212
        int r = e >> 8, d = e & 255;
        float4 v = *(const float4*)(gI + e);
        *(float4*)&sI[r * PI + d] = v;
    }
    // ---- stage captions[c0..c0+G-1] -> sC (pitch 257 => scalar writes) ----
    const float* gC = captions + (size_t)c0 * NW * ND;
    #pragma unroll
    for (int q = 0; q < 24; ++q) {
        int e = (q * 256 + tid) * 4;           // 0..24572
        int w = e >> 8, d = e & 255;
        float4 v = *(const float4*)(gC + e);
        float* p = &sC[w * PC + d];
        p[0] = v.x; p[1] = v.y; p[2] = v.z; p[3] = v.w;
    }
    __syncthreads();

    // ---- phase 1: attn[r][wg] = leakyrelu(dot(img_r, cap_wg)), 4x4 tiles ----
    {
        int wt = tid % 24, rt = tid / 24;      // 9 x 24 = 216 active threads
        if (rt < 9) {
            int r0 = rt * 4, w0 = wt * 4;
            float acc[4][4] = {};
            for (int d0 = 0; d0 < ND; d0 += 4) {
                float4 ar[4];
                #pragma unroll
                for (int k = 0; k < 4; ++k)
                    ar[k] = *(const float4*)&sI[(r0 + k) * PI + d0];
                #pragma unroll
                for (int l = 0; l < 4; ++l) {
                    const float* bp = &sC[(w0 + l) * PC + d0];
                    float b0 = bp[0], b1 = bp[1], b2 = bp[2], b3 = bp[3];
                    #pragma unroll
                    for (int k = 0; k < 4; ++k)
                        acc[k][l] += ar[k].x * b0 + ar[k].y * b1
                                   + ar[k].z * b2 + ar[k].w * b3;
                }
            }
            #pragma unroll
            for (int k = 0; k < 4; ++k) {
                #pragma unroll
                for (int l = 0; l < 4; ++l) {
                    float x = acc[k][l];
                    x = x > 0.f ? x : 0.1f * x;          // leaky_relu 0.1
                    int wg = w0 + l;                      // 0..95 (tile never straddles cg)
                    int cg = wg / NW, w = wg % NW;
                    sA[cg * 1800 + (r0 + k) * PA + w] = x;
                }
            }
        }
    }
    __syncthreads();

    // ---- per-(cg,r) l2 norm over w ----
    if (tid < G * NR) {
        int cg = tid / NR, r = tid % NR;
        const float* row = &sA[cg * 1800 + r * PA];
        float ss = 0.f;
        #pragma unroll
        for (int w = 0; w < NW; ++w) { float x = row[w]; ss += x * x; }
        invn[tid] = 1.f / (sqrtf(ss) + 1e-8f);
    }
    __syncthreads();

    // ---- softmax over r per (cg,w); write transposed pT overlaid on sA ----
    {
        float p[NR];
        int cg = tid / NW, w = tid % NW;
        bool act = tid < NWG;
        if (act) {
            float m = -1e30f;
            #pragma unroll
            for (int r = 0; r < NR; ++r) {
                float x = sA[cg * 1800 + r * PA + w] * invn[cg * NR + r] * 9.0f;
                p[r] = x;
                m = fmaxf(m, x);
            }
            float s = 0.f;
            #pragma unroll
            for (int r = 0; r < NR; ++r) { float e = __expf(p[r] - m); p[r] = e; s += e; }
            float is = 1.f / s;
            #pragma unroll
            for (int r = 0; r < NR; ++r) p[r] *= is;
        }
        __syncthreads();   // all reads of attn layout done before overwrite
        if (act) {
            #pragma unroll
            for (int r = 0; r < NR; ++r)
                sA[cg * 1776 + w * PP + r] = p[r];
        }
        if (tid < NWG) { w12s[tid] = 0.f; w2s[tid] = 0.f; }
    }
    __syncthreads();

    // ---- phase 2: wctx[w][d] = sum_r pT[w][r]*sI[r][d]; fold cosine partials ----
    {
        int wg = tid & 15, dc = tid >> 4;      // 16 w-groups x 16 d-chunks
        int d0 = dc * 16;
        float acc[G][3][16] = {};
        for (int r = 0; r < NR; ++r) {
            float4 af[4];
            #pragma unroll
            for (int k4 = 0; k4 < 4; ++k4)
                af[k4] = *(const float4*)&sI[r * PI + d0 + 4 * k4];
            #pragma unroll
            for (int cg = 0; cg < G; ++cg) {
                #pragma unroll
                for (int j = 0; j < 3; ++j) {
                    float pv = sA[cg * 1776 + (wg * 3 + j) * PP + r];
                    float* a = acc[cg][j];
                    #pragma unroll
                    for (int k4 = 0; k4 < 4; ++k4) {
                        a[4*k4+0] += pv * af[k4].x;
                        a[4*k4+1] += pv * af[k4].y;
                        a[4*k4+2] += pv * af[k4].z;
                        a[4*k4+3] += pv * af[k4].w;
                    }
                }
            }
        }
        #pragma unroll
        for (int cg = 0; cg < G; ++cg) {
            #pragma unroll
            for (int j = 0; j < 3; ++j) {
                int w = wg * 3 + j;
                const float* crow = &sC[(cg * NW + w) * PC + d0];
                float p12 = 0.f, p2 = 0.f;
                #pragma unroll
                for (int k = 0; k < 16; ++k) {
                    float v = acc[cg][j][k];
                    p12 += crow[k] * v;
                    p2  += v * v;
                }
                atomicAdd(&w12s[cg * NW + w], p12);
                atomicAdd(&w2s[cg * NW + w], p2);
            }
        }
    }
    __syncthreads();

    // ---- row_sim = w12 / max(|cap| * |wctx|, eps) ----
    if (tid < NWG) {
        const float* crow = &sC[tid * PC];
        float ss = 0.f;
        for (int d = 0; d < ND; ++d) { float v = crow[d]; ss += v * v; }
        float w1 = sqrtf(ss);
        float w2 = sqrtf(w2s[tid]);
        rs[tid] = w12s[tid] / fmaxf(w1 * w2, 1e-8f);
    }
    __syncthreads();

    // ---- LSE over w, write out[i][c] ----
    if (tid < G) {
        const float* r0 = &rs[tid * NW];
        float m = -1e30f;
        for (int w = 0; w < NW; ++w) m = fmaxf(m, 6.0f * r0[w]);
        float s = 0.f;
        for (int w = 0; w < NW; ++w) s += __expf(6.0f * r0[w] - m);
        out[(size_t)i * NC + (c0 + tid)] = (m + logf(s)) / 6.0f;
    }
}

extern "C" void kernel_launch(void* const* d_in, const int* in_sizes, int n_in,
                              void* d_out, int out_size, void* d_ws, size_t ws_size,
                              hipStream_t stream) {
    const float* images   = (const float*)d_in[0];   // (128, 36, 256) fp32
    const float* captions = (const float*)d_in[1];   // (256, 48, 256) fp32
    float* out = (float*)d_out;                      // (128, 256) fp32

    dim3 grid(NC / G, NI);   // 128 x 128
    dim3 block(256);
    hipLaunchKernelGGL(scan_kernel, grid, block, 0, stream, images, captions, out);
}

// Round 2
// 810.548 us; speedup vs baseline: 2.3153x; 2.3153x over previous
//
#include <hip/hip_runtime.h>
#include <math.h>

#define NI 128
#define NC 256
#define NR 36
#define NW 48
#define ND 256
#define G  2            // captions per block

// LDS pitches
#define PIB 264         // sIb bf16 pitch ([r][d], 48 rows, rows 36..47 zeroed)
#define PCB 264         // sCb bf16 pitch ([cg*48+w][d])
#define PA  49          // sA fp32 pitch ([cg][r][w])
#define PPB 72          // sP bf16 pitch ([cg*48+w][r], k-pad r=36..63 zeroed)
#define PTB 72          // sIT bf16 pitch ([d][r], k-pad zeroed)

typedef __bf16 bf16x8 __attribute__((ext_vector_type(8)));
typedef __bf16 bf16x4 __attribute__((ext_vector_type(4)));
typedef float  f32x4  __attribute__((ext_vector_type(4)));

__global__ __launch_bounds__(1024, 1)
void scan_kernel(const float* __restrict__ images,
                 const float* __restrict__ captions,
                 float* __restrict__ out)
{
    // 142,272 B total — 1 block/CU, 16 waves (4/SIMD)
    __shared__ __align__(16) __bf16 sIb[48 * PIB];       // 25,344 B
    __shared__ __align__(16) __bf16 sIT[ND * PTB];       // 36,864 B
    __shared__ __align__(16) __bf16 sCb[G * NW * PCB];   // 50,688 B
    __shared__ __align__(16) float  sA [G * NR * PA];    // 14,112 B
    __shared__ __align__(16) __bf16 sP [G * NW * PPB];   // 13,824 B
    __shared__ float invn[G * NR];
    __shared__ float w12s[G * NW];
    __shared__ float w2s [G * NW];
    __shared__ float rs  [G * NW];

    const int tid  = threadIdx.x;
    const int wave = tid >> 6;
    const int lane = tid & 63;
    const int quad = lane >> 4;
    const int l15  = lane & 15;
    const int i    = blockIdx.y;
    const int c0   = blockIdx.x * G;

    // ---- zero k-pad regions (sIT, sP, sIb rows 36..47) + accumulators ----
    {
        uint32_t* pIT = (uint32_t*)sIT;            // 9216 words
        #pragma unroll
        for (int k = 0; k < 9; ++k) pIT[tid + k * 1024] = 0u;
        uint32_t* pP = (uint32_t*)sP;              // 3456 words
        #pragma unroll
        for (int k = 0; k < 4; ++k) { int x = tid + k * 1024; if (x < 3456) pP[x] = 0u; }
        uint32_t* pIb = (uint32_t*)sIb;            // pad words 4752..6335
        #pragma unroll
        for (int k = 0; k < 2; ++k) { int x = tid + k * 1024; if (x < 1584) pIb[4752 + x] = 0u; }
        if (tid < G * NW) { w12s[tid] = 0.f; w2s[tid] = 0.f; }
    }
    __syncthreads();

    // ---- stage images -> sIb[r][d] bf16, captions -> sCb (coalesced float4) ----
    const float* gI = images + (size_t)i * NR * ND;
    #pragma unroll
    for (int k = 0; k < 3; ++k) {
        int idx = tid + k * 1024;                  // 2304 float4
        if (idx < 2304) {
            int e = idx * 4, r = e >> 8, d = e & 255;
            float4 v = *(const float4*)(gI + e);
            bf16x4 h; h.x = (__bf16)v.x; h.y = (__bf16)v.y; h.z = (__bf16)v.z; h.w = (__bf16)v.w;
            *(bf16x4*)&sIb[r * PIB + d] = h;
        }
    }
    const float* gC = captions + (size_t)c0 * NW * ND;
    #pragma unroll
    for (int k = 0; k < 6; ++k) {
        int idx = tid + k * 1024;                  // 6144 float4
        int e = idx * 4, cw = e >> 8, d = e & 255;
        float4 v = *(const float4*)(gC + e);
        bf16x4 h; h.x = (__bf16)v.x; h.y = (__bf16)v.y; h.z = (__bf16)v.z; h.w = (__bf16)v.w;
        *(bf16x4*)&sCb[cw * PCB + d] = h;
    }
    __syncthreads();

    // ---- phase 1: attn[r][w] = leakyrelu(I·capT), 18 MFMA tiles ----
    for (int t = wave; t < G * 9; t += 16) {
        int cg = t / 9, rest = t % 9, mt = rest / 3, nt = rest % 3;
        int arow = mt * 16 + l15;                  // sIb row (rows>=36 are zero pad)
        int brow = cg * NW + nt * 16 + l15;        // sCb row
        f32x4 acc = {0.f, 0.f, 0.f, 0.f};
        #pragma unroll
        for (int k0 = 0; k0 < ND; k0 += 32) {
            bf16x8 a = *(const bf16x8*)&sIb[arow * PIB + k0 + quad * 8];
            bf16x8 b = *(const bf16x8*)&sCb[brow * PCB + k0 + quad * 8];
            acc = __builtin_amdgcn_mfma_f32_16x16x32_bf16(a, b, acc, 0, 0, 0);
        }
        #pragma unroll
        for (int p = 0; p < 4; ++p) {
            int row = mt * 16 + quad * 4 + p;      // r
            if (row < NR) {
                float x = acc[p];
                x = x > 0.f ? x : 0.1f * x;        // leaky_relu(0.1)
                sA[cg * (NR * PA) + row * PA + nt * 16 + l15] = x;
            }
        }
    }
    // ---- build sIT[d][r] (transpose of sIb) while other waves finish phase 1 ----
    #pragma unroll
    for (int k = 0; k < 3; ++k) {
        int t = tid + k * 1024;                    // 2304 = 256 d x 9 r-quads
        if (t < 2304) {
            int d = t & 255, r0 = (t >> 8) * 4;
            bf16x4 h;
            h.x = sIb[(r0 + 0) * PIB + d];
            h.y = sIb[(r0 + 1) * PIB + d];
            h.z = sIb[(r0 + 2) * PIB + d];
            h.w = sIb[(r0 + 3) * PIB + d];
            *(bf16x4*)&sIT[d * PTB + r0] = h;
        }
    }
    __syncthreads();

    // ---- per-(cg,r) l2 norm over w ----
    if (tid < G * NR) {
        int cg = tid / NR, r = tid % NR;
        const float* row = &sA[cg * (NR * PA) + r * PA];
        float ss = 0.f;
        #pragma unroll
        for (int w = 0; w < NW; ++w) { float x = row[w]; ss += x * x; }
        invn[tid] = 1.f / (sqrtf(ss) + 1e-8f);
    }
    __syncthreads();

    // ---- softmax over r per (cg,w); write P[w][r] bf16 (r-contiguous) ----
    if (tid < G * NW) {
        int cg = tid / NW, w = tid % NW;
        float p[NR];
        float m = -1e30f;
        #pragma unroll
        for (int r = 0; r < NR; ++r) {
            float x = sA[cg * (NR * PA) + r * PA + w] * invn[cg * NR + r] * 9.0f;
            p[r] = x; m = fmaxf(m, x);
        }
        float s = 0.f;
        #pragma unroll
        for (int r = 0; r < NR; ++r) { float e = __expf(p[r] - m); p[r] = e; s += e; }
        float is = 1.f / s;
        __bf16* dst = &sP[(cg * NW + w) * PPB];
        #pragma unroll
        for (int r = 0; r < NR; ++r) dst[r] = (__bf16)(p[r] * is);
    }
    __syncthreads();

    // ---- phase 2: wctx[w][d] = P·I  (K=36 padded to 64); fused cosine partials ----
    // 24 jobs: (cg, mt, ng) each = 1 A-frag row-tile x 4 d-tiles
    for (int j = wave; j < 24; j += 16) {
        int cg = j / 12, rem = j % 12, mt = rem / 4, ng = rem % 4;
        int aoff = (cg * NW + mt * 16 + l15) * PPB;
        f32x4 acc[4] = {{0,0,0,0},{0,0,0,0},{0,0,0,0},{0,0,0,0}};
        #pragma unroll
        for (int kk = 0; kk < 64; kk += 32) {
            bf16x8 a = *(const bf16x8*)&sP[aoff + kk + quad * 8];
            #pragma unroll
            for (int u = 0; u < 4; ++u) {
                int drow = (ng * 4 + u) * 16 + l15;
                bf16x8 b = *(const bf16x8*)&sIT[drow * PTB + kk + quad * 8];
                acc[u] = __builtin_amdgcn_mfma_f32_16x16x32_bf16(a, b, acc[u], 0, 0, 0);
            }
        }
        float p12[4] = {0.f, 0.f, 0.f, 0.f};
        float p2 [4] = {0.f, 0.f, 0.f, 0.f};
        #pragma unroll
        for (int u = 0; u < 4; ++u) {
            int d = (ng * 4 + u) * 16 + l15;
            #pragma unroll
            for (int p = 0; p < 4; ++p) {
                int w = mt * 16 + quad * 4 + p;
                float v = acc[u][p];
                float c = (float)sCb[(cg * NW + w) * PCB + d];
                p12[p] += c * v;
                p2 [p] += v * v;
            }
        }
        #pragma unroll
        for (int p = 0; p < 4; ++p) {
            #pragma unroll
            for (int off = 8; off > 0; off >>= 1) {
                p12[p] += __shfl_xor(p12[p], off);
                p2 [p] += __shfl_xor(p2 [p], off);
            }
        }
        if (l15 == 0) {
            #pragma unroll
            for (int p = 0; p < 4; ++p) {
                int w = cg * NW + mt * 16 + quad * 4 + p;
                atomicAdd(&w12s[w], p12[p]);
                atomicAdd(&w2s [w], p2 [p]);
            }
        }
    }
    __syncthreads();

    // ---- row_sim = w12 / max(|cap|*|wctx|, eps) ----
    if (tid < G * NW) {
        const __bf16* crow = &sCb[tid * PCB];
        float ss = 0.f;
        for (int d = 0; d < ND; ++d) { float v = (float)crow[d]; ss += v * v; }
        float w1 = sqrtf(ss);
        float w2 = sqrtf(w2s[tid]);
        rs[tid] = w12s[tid] / fmaxf(w1 * w2, 1e-8f);
    }
    __syncthreads();

    // ---- LSE over w, write out[i][c] ----
    if (tid < G) {
        const float* r0 = &rs[tid * NW];
        float m = -1e30f;
        for (int w = 0; w < NW; ++w) m = fmaxf(m, 6.0f * r0[w]);
        float s = 0.f;
        for (int w = 0; w < NW; ++w) s += __expf(6.0f * r0[w] - m);
        out[(size_t)i * NC + (c0 + tid)] = (m + logf(s)) / 6.0f;
    }
}

extern "C" void kernel_launch(void* const* d_in, const int* in_sizes, int n_in,
                              void* d_out, int out_size, void* d_ws, size_t ws_size,
                              hipStream_t stream) {
    const float* images   = (const float*)d_in[0];   // (128, 36, 256) fp32
    const float* captions = (const float*)d_in[1];   // (256, 48, 256) fp32
    float* out = (float*)d_out;                      // (128, 256) fp32

    dim3 grid(NC / G, NI);   // 128 x 128 (gridDim.x%8==0 -> caption group pinned per XCD)
    dim3 block(1024);
    hipLaunchKernelGGL(scan_kernel, grid, block, 0, stream, images, captions, out);
}